// Round 3
// baseline (254.726 us; speedup 1.0000x reference)
//
#include <hip/hip_runtime.h>

#define FEPS 1e-12f

typedef __attribute__((ext_vector_type(8))) short short8;   // 8 bf16 = 4 VGPR
typedef __attribute__((ext_vector_type(4))) float floatx4;  // MFMA C/D

constexpr int NB = 64, D = 256, T = 4096, K = 64, S = 8;
constexpr int TBLK = T / S;     // 512 pixels per block
constexpr int TC = 64;          // pixels per chunk
constexpr int NCH = TBLK / TC;  // 8 chunks

// f32 -> bf16 round-to-nearest-even
__device__ __forceinline__ unsigned short f2bf(float f) {
    unsigned u = __float_as_uint(f);
    return (unsigned short)((u + 0x7FFFu + ((u >> 16) & 1u)) >> 16);
}
__device__ __forceinline__ unsigned pk2(float a, float b) {
    return (unsigned)f2bf(a) | ((unsigned)f2bf(b) << 16);
}

// Workgroup barrier WITHOUT the implicit vmcnt(0) drain __syncthreads emits.
// lgkmcnt(0) orders our ds_writes before the barrier; the asm memory clobber
// keeps all memory ops (incl. DS) from crossing; register-destined global
// prefetch loads legally remain in flight across it.
__device__ __forceinline__ void barrier_nodrain() {
    __builtin_amdgcn_sched_barrier(0);
    asm volatile("s_waitcnt lgkmcnt(0)" ::: "memory");
    __builtin_amdgcn_s_barrier();
    __builtin_amdgcn_sched_barrier(0);
}

// Fused: L2-norm factor + logits MFMA-GEMM + softmax + aggregation MFMA-GEMM.
// grid = (S, NB), block = 256 (4 waves). LDS ~74 KB -> 2 blocks/CU.
// Global loads for chunk c+1 are register-prefetched during chunk c compute.
__global__ __launch_bounds__(256, 2)
void nv_main(const float* __restrict__ x, const float* __restrict__ w,
             float* __restrict__ vlad, float* __restrict__ suma)
{
    __shared__ unsigned short xs1[TC * D];  // [t][d ^ 8*(t&31)]  GEMM1 B
    __shared__ unsigned short xs2[D * TC];  // [d][t ^ 8*(d&7)]   GEMM2 B
    __shared__ unsigned short bm[K * TC];   // [k][t ^ 8*(k&7)]   GEMM2 A
    __shared__ float sps[TC][4];            // per-wave softmax denom partials
    __shared__ float sqp[4][TC];            // per-wave sumsq partials

    const int tid = threadIdx.x;
    const int wv = tid >> 6, ln = tid & 63;
    const int m = ln & 15, g = ln >> 4;
    const int n = blockIdx.y;

    const float* xn = x + (size_t)n * D * T;

    // Resident W A-frags: wave wv owns GEMM1 m-tile = clusters [16wv,16wv+16)
    short8 wf[8];
    {
        const float* wp = w + (16 * wv + m) * D + 8 * g;
        #pragma unroll
        for (int ks = 0; ks < 8; ++ks) {
            float4 q0 = *(const float4*)(wp + 32 * ks);
            float4 q1 = *(const float4*)(wp + 32 * ks + 4);
            union { short8 v; unsigned u[4]; } t_;
            t_.u[0] = pk2(q0.x, q0.y); t_.u[1] = pk2(q0.z, q0.w);
            t_.u[2] = pk2(q1.x, q1.y); t_.u[3] = pk2(q1.z, q1.w);
            wf[ks] = t_.v;
        }
    }

    floatx4 acc[4][4];                       // GEMM2 acc [mt(k)][nt(d)]
    floatx4 fzero = {0.f, 0.f, 0.f, 0.f};
    #pragma unroll
    for (int a = 0; a < 4; ++a)
        #pragma unroll
        for (int b = 0; b < 4; ++b) acc[a][b] = fzero;
    float sa[4] = {0.f, 0.f, 0.f, 0.f};      // sum_t a for k = 16wv+4g+reg

    // ---- prologue: prefetch chunk 0 into registers
    float4 pv[16];
    {
        const int t0 = blockIdx.x * TBLK;
        #pragma unroll
        for (int s = 0; s < 16; ++s) {
            const int d = 64 * wv + 4 * s + g;
            pv[s] = *(const float4*)(xn + (size_t)d * T + t0 + 4 * m);
        }
    }

    for (int c = 0; c < NCH; ++c) {
        barrier_nodrain();                   // xs/sqp free (prev chunk done)

        // ---- stage: pv (f32) -> bf16 into xs1 (via 4x4 lane-transpose) + xs2
        float4 sq4 = {0.f, 0.f, 0.f, 0.f};
        #pragma unroll
        for (int s = 0; s < 16; ++s) {
            const int d = 64 * wv + 4 * s + g;
            float4 v = pv[s];
            sq4.x = fmaf(v.x, v.x, sq4.x); sq4.y = fmaf(v.y, v.y, sq4.y);
            sq4.z = fmaf(v.z, v.z, sq4.z); sq4.w = fmaf(v.w, v.w, sq4.w);
            unsigned lo = pk2(v.x, v.y), hi = pk2(v.z, v.w);
            uint2 st2; st2.x = lo; st2.y = hi;          // 4 bf16, t-contiguous
            *(uint2*)(&xs2[d * TC + ((4 * m) ^ (8 * (d & 7)))]) = st2;
            // 4x4 bf16 transpose across lanes {m, g=0..3} (d rows <-> t cols)
            unsigned plo = __shfl_xor(lo, 16), phi = __shfl_xor(hi, 16);
            unsigned lo1, hi1;
            if ((g & 1) == 0) { lo1 = (lo & 0xFFFFu) | (plo << 16);
                                hi1 = (hi & 0xFFFFu) | (phi << 16); }
            else              { lo1 = (lo >> 16) | (plo & 0xFFFF0000u);
                                hi1 = (hi >> 16) | (phi & 0xFFFF0000u); }
            unsigned slo = __shfl_xor(lo1, 32), shi = __shfl_xor(hi1, 32);
            uint2 ot;
            if ((g & 2) == 0) { ot.x = lo1; ot.y = slo; }
            else              { ot.x = shi; ot.y = hi1; }
            const int tt = 4 * m + g;                   // t this lane now owns
            const int db = 64 * wv + 4 * s;             // 4 d's, ascending
            *(uint2*)(&xs1[tt * D + (db ^ (8 * (tt & 31)))]) = ot;
        }
        // per-t sumsq partial (this wave's 64 d's): reduce over g
        sq4.x += __shfl_xor(sq4.x, 16); sq4.y += __shfl_xor(sq4.y, 16);
        sq4.z += __shfl_xor(sq4.z, 16); sq4.w += __shfl_xor(sq4.w, 16);
        sq4.x += __shfl_xor(sq4.x, 32); sq4.y += __shfl_xor(sq4.y, 32);
        sq4.z += __shfl_xor(sq4.z, 32); sq4.w += __shfl_xor(sq4.w, 32);
        if (g == 0) *(float4*)(&sqp[wv][4 * m]) = sq4;
        barrier_nodrain();                   // publish xs1/xs2/sqp

        // ---- prefetch chunk c+1 (in flight across GEMM1/softmax/GEMM2)
        {
            const int cn = (c + 1 < NCH) ? (c + 1) : c;  // last: benign reload
            const int tn = blockIdx.x * TBLK + cn * TC;
            #pragma unroll
            for (int s = 0; s < 16; ++s) {
                const int d = 64 * wv + 4 * s + g;
                pv[s] = *(const float4*)(xn + (size_t)d * T + tn + 4 * m);
            }
        }

        // ---- r[t] = 1/max(||x[:,t]||,eps) for this lane's 4 t-columns
        float r4[4];
        #pragma unroll
        for (int nt = 0; nt < 4; ++nt) {
            const int t = 16 * nt + m;
            float ss = sqp[0][t] + sqp[1][t] + sqp[2][t] + sqp[3][t];
            r4[nt] = 1.f / fmaxf(sqrtf(ss), FEPS);
        }

        // ---- GEMM1: z[16wv..+16 k][64 t] = W * x  (contract d=256)
        floatx4 z[4];
        #pragma unroll
        for (int nt = 0; nt < 4; ++nt) z[nt] = fzero;
        #pragma unroll
        for (int ks = 0; ks < 8; ++ks) {
            #pragma unroll
            for (int nt = 0; nt < 4; ++nt) {
                const int t = 16 * nt + m;
                short8 bfr = *(const short8*)(
                    &xs1[t * D + ((32 * ks + 8 * g) ^ (8 * (t & 31)))]);
                z[nt] = __builtin_amdgcn_mfma_f32_16x16x32_bf16(
                    wf[ks], bfr, z[nt], 0, 0, 0);
            }
        }

        // ---- softmax over k (no max-sub: |logit| <= |w_row| ~ 1)
        float e[4][4], psum[4];
        #pragma unroll
        for (int nt = 0; nt < 4; ++nt) {
            const float r = r4[nt];
            float p = 0.f;
            #pragma unroll
            for (int reg = 0; reg < 4; ++reg) {
                float ex = __expf(z[nt][reg] * r);
                e[nt][reg] = ex; p += ex;
            }
            psum[nt] = p;
        }
        #pragma unroll
        for (int nt = 0; nt < 4; ++nt) {     // reduce over g: wave's 16 k's
            psum[nt] += __shfl_xor(psum[nt], 16);
            psum[nt] += __shfl_xor(psum[nt], 32);
        }
        if (g == 0) {
            #pragma unroll
            for (int nt = 0; nt < 4; ++nt) sps[16 * nt + m][wv] = psum[nt];
        }
        barrier_nodrain();                   // publish sps
        #pragma unroll
        for (int nt = 0; nt < 4; ++nt) {
            const int t = 16 * nt + m;
            float4 sv = *(const float4*)(&sps[t][0]);
            const float inv = 1.f / (sv.x + sv.y + sv.z + sv.w);
            const float br = inv * r4[nt];
            #pragma unroll
            for (int reg = 0; reg < 4; ++reg) {
                const int k = 16 * wv + 4 * g + reg;
                bm[k * TC + (t ^ (8 * (k & 7)))] = f2bf(e[nt][reg] * br);
                sa[reg] += e[nt][reg] * inv;
            }
        }
        barrier_nodrain();                   // publish bm

        // ---- GEMM2: acc[k][d] += b[k][t] * x[d][t]  (contract t=64)
        #pragma unroll
        for (int kt = 0; kt < 2; ++kt) {
            short8 af[4], bf[4];
            #pragma unroll
            for (int mt = 0; mt < 4; ++mt) {
                const int k = 16 * mt + m;
                af[mt] = *(const short8*)(
                    &bm[k * TC + ((32 * kt + 8 * g) ^ (8 * (k & 7)))]);
            }
            #pragma unroll
            for (int nt = 0; nt < 4; ++nt) {
                const int d = 64 * wv + 16 * nt + m;
                bf[nt] = *(const short8*)(
                    &xs2[d * TC + ((32 * kt + 8 * g) ^ (8 * (d & 7)))]);
            }
            #pragma unroll
            for (int mt = 0; mt < 4; ++mt)
                #pragma unroll
                for (int nt = 0; nt < 4; ++nt)
                    acc[mt][nt] = __builtin_amdgcn_mfma_f32_16x16x32_bf16(
                        af[mt], bf[nt], acc[mt][nt], 0, 0, 0);
        }
    }

    // ---- flush vlad partials (8 t-split blocks per n) + suma
    float* vout = vlad + (size_t)n * K * D;
    #pragma unroll
    for (int mt = 0; mt < 4; ++mt)
        #pragma unroll
        for (int nt = 0; nt < 4; ++nt)
            #pragma unroll
            for (int reg = 0; reg < 4; ++reg)
                atomicAdd(&vout[(16 * mt + 4 * g + reg) * D
                                + 64 * wv + 16 * nt + m], acc[mt][nt][reg]);
    #pragma unroll
    for (int reg = 0; reg < 4; ++reg) {
        float v = sa[reg];
        v += __shfl_xor(v, 1); v += __shfl_xor(v, 2);
        v += __shfl_xor(v, 4); v += __shfl_xor(v, 8);
        if (m == 0) atomicAdd(&suma[n * K + 16 * wv + 4 * g + reg], v);
    }
}

// per (n,k): subtract suma*centroid, intra-normalize over d, accum final sumsq
__global__ void nv_finish_row(const float* __restrict__ cent,
                              const float* __restrict__ suma,
                              float* __restrict__ out,
                              float* __restrict__ nsum)
{
    const int bid = blockIdx.x;          // n*64 + k
    const int k = bid & 63;
    const int d = threadIdx.x;
    float v = out[(size_t)bid * 256 + d] - suma[bid] * cent[k * 256 + d];
    float sv = v * v;
    #pragma unroll
    for (int msk = 1; msk < 64; msk <<= 1) sv += __shfl_xor(sv, msk);
    __shared__ float red[4];
    __shared__ float stot;
    if ((d & 63) == 0) red[d >> 6] = sv;
    __syncthreads();
    if (d == 0) stot = red[0] + red[1] + red[2] + red[3];
    __syncthreads();
    const float s = stot;
    const float inv = 1.f / fmaxf(sqrtf(s), FEPS);
    out[(size_t)bid * 256 + d] = v * inv;
    if (d == 0) atomicAdd(&nsum[bid >> 6], s * inv * inv);
}

// final L2 over the flattened (K*D) per n
__global__ void nv_final(float* __restrict__ out, const float* __restrict__ nsum) {
    const int idx = blockIdx.x * 256 + threadIdx.x;
    const int n = idx >> 14;             // /16384
    out[idx] *= 1.f / fmaxf(sqrtf(nsum[n]), FEPS);
}

extern "C" void kernel_launch(void* const* d_in, const int* in_sizes, int n_in,
                              void* d_out, int out_size, void* d_ws, size_t ws_size,
                              hipStream_t stream)
{
    const float* x    = (const float*)d_in[0];
    const float* w    = (const float*)d_in[1];
    const float* cent = (const float*)d_in[2];
    float* out = (float*)d_out;

    // ws layout: suma[NB*K] | nsum[NB] (padded region to 1KB)
    float* suma = (float*)d_ws;
    float* nsum = (float*)((char*)d_ws + (size_t)NB * K * 4);

    hipMemsetAsync(d_ws, 0, (size_t)NB * K * 4 + 1024, stream);
    hipMemsetAsync(d_out, 0, (size_t)NB * K * D * sizeof(float), stream);

    dim3 g(S, NB);
    nv_main<<<g, 256, 0, stream>>>(x, w, out, suma);
    nv_finish_row<<<NB * K, 256, 0, stream>>>(cent, suma, out, nsum);
    nv_final<<<(NB * K * D) / 256, 256, 0, stream>>>(out, nsum);
}